// Round 4
// baseline (126.069 us; speedup 1.0000x reference)
//
#include <hip/hip_runtime.h>
#include <hip/hip_bf16.h>

#define NB 64
#define NS 1024
#define DD 256
#define BM 128
#define BK 32
#define NT 36          // upper-triangular 8x8 tile count
#define GB 2           // batches per block
#define THR 120.0f     // dist^2 below which exp(-dist) can matter

typedef __attribute__((ext_vector_type(4))) float f32x4;
typedef __attribute__((ext_vector_type(8))) short bf16x8;
typedef __attribute__((ext_vector_type(8))) unsigned short u16x8;
typedef __attribute__((ext_vector_type(4))) unsigned short u16x4;

__device__ __forceinline__ unsigned short f2bf(float x) {
  union { float f; unsigned int u; } c; c.f = x;
  unsigned int r = c.u + 0x7fffu + ((c.u >> 16) & 1u);
  return (unsigned short)(r >> 16);
}

// ---- fused prep (sq + bf16 copy) and denom/C reduction ----
// blocks [0, 16384): prep rows; blocks [16384, 17408): denom + C
__global__ __launch_bounds__(256) void prep_kernel(const float* __restrict__ din,
                                                   unsigned short* __restrict__ dbf,
                                                   float* __restrict__ sq,
                                                   const float* __restrict__ S,
                                                   const float* __restrict__ W,
                                                   float* __restrict__ denom2,
                                                   float* __restrict__ Cval,
                                                   int write_bf) {
  if (blockIdx.x >= 16384) {
    const int t = ((int)blockIdx.x - 16384) * 256 + threadIdx.x;
    float4 w = reinterpret_cast<const float4*>(W)[t];
    float4 s = reinterpret_cast<const float4*>(S)[t];
    const int e0 = t << 2;
    const int r = e0 >> 10, c0 = e0 & 1023;
    float dsum = 0.f, csum = 0.f;
    float wv[4] = {w.x, w.y, w.z, w.w};
    float sv[4] = {s.x, s.y, s.z, s.w};
    #pragma unroll
    for (int i = 0; i < 4; ++i) {
      const bool dg = (c0 + i) == r;
      const float a = wv[i] - (dg ? 1.0f : 0.0f);
      dsum = fmaf(a, a, dsum);
      const float b = dg ? (1.0f - sv[i]) : sv[i];
      csum = fmaf(wv[i] * b, b, csum);   // W binary: W^2 == W
    }
    #pragma unroll
    for (int off = 32; off > 0; off >>= 1) {
      dsum += __shfl_xor(dsum, off, 64);
      csum += __shfl_xor(csum, off, 64);
    }
    __shared__ float redD[4], redC[4];
    if ((threadIdx.x & 63) == 0) { redD[threadIdx.x >> 6] = dsum; redC[threadIdx.x >> 6] = csum; }
    __syncthreads();
    if (threadIdx.x == 0) {
      atomicAdd(denom2, redD[0] + redD[1] + redD[2] + redD[3]);
      atomicAdd(Cval, redC[0] + redC[1] + redC[2] + redC[3]);
    }
    return;
  }
  const int row = blockIdx.x * 4 + (threadIdx.x >> 6);
  const int lane = threadIdx.x & 63;
  const float4* src = reinterpret_cast<const float4*>(din + (size_t)row * DD);
  float4 v = src[lane];
  float s = v.x * v.x + v.y * v.y + v.z * v.z + v.w * v.w;
  if (write_bf) {
    u16x4 o;
    o[0] = f2bf(v.x); o[1] = f2bf(v.y); o[2] = f2bf(v.z); o[3] = f2bf(v.w);
    reinterpret_cast<u16x4*>(dbf + (size_t)row * DD)[lane] = o;
  }
  #pragma unroll
  for (int off = 32; off > 0; off >>= 1) s += __shfl_xor(s, off, 64);
  if (lane == 0) sq[row] = s;
}

// ---- main: upper-triangular Gram tiles, MFMA, near-empty epilogue ----
// BK=32: LDS = 2buf x (A+B) x 8KB = 32KB -> 4+ blocks/CU for latency overlap.
// LDS tiles [128][32] bf16, 16B-chunk swizzle: data chunk cd of row r lives at
// LDS chunk cd ^ ((r>>1)&3). global_load_lds dest stays LINEAR; the inverse
// permutation is applied to the per-lane GLOBAL source (rule #21).
template <int MODE>
__global__ __launch_bounds__(256, 4) void main_kernel(
    const float* __restrict__ dvec, const unsigned short* __restrict__ dbf,
    const float* __restrict__ sq, const float* __restrict__ S,
    const float* __restrict__ W, float* __restrict__ numer2) {
  __shared__ unsigned short As[2][BM * BK];
  __shared__ unsigned short Bs[2][BM * BK];

  const int tid = threadIdx.x;
  const int lane = tid & 63;
  const int wid = tid >> 6;
  const int wr = wid >> 1;
  const int wc = wid & 1;

  // T1: XCD-chunked bijective swizzle (1152 = 8 * 144): each XCD owns 4
  // complete batch-groups -> panel set stays in its 4MB L2.
  const int orig = (int)blockIdx.x;
  const int bid = (orig & 7) * (NT * (NB / GB) / 8) + (orig >> 3);
  const int t = bid % NT;
  const int g = bid / NT;
  int u = t, ti = 0;
  while (u >= 8 - ti) { u -= 8 - ti; ++ti; }
  const int tj = ti + u;
  const int brow = ti * BM;
  const int bcol = tj * BM;
  const bool diag = (ti == tj);
  const int b0 = g * GB;

  // staging: thread writes LDS linear chunk (q*256 + tid) -> row = q*64 + (tid>>2),
  // lds chunk-in-row = tid&3. Source data chunk = (tid&3) ^ ((row>>1)&3)
  //   = (tid&3) ^ ((tid>>3)&3)   (q*64 rows -> (q*32)&3 == 0, q-independent)
  const int srow = tid >> 2;                                  // + q*64
  const int scol = (((tid & 3) ^ ((tid >> 3) & 3)) * 8);      // element offset

  f32x4 acc[4][4];
  #pragma unroll
  for (int m = 0; m < 4; ++m)
    #pragma unroll
    for (int n = 0; n < 4; ++n) acc[m][n] = f32x4{0.f, 0.f, 0.f, 0.f};

  auto STAGE = [&](int buf, int it) {
    const int b = b0 + (it >> 3);
    const int kk = (it & 7) * BK;
    if (MODE == 0) {
      const unsigned short* base = dbf + (size_t)b * (NS * DD) + kk + scol;
      #pragma unroll
      for (int q = 0; q < 2; ++q) {
        const int row = q * 64 + srow;
        const unsigned short* ga = base + (size_t)(brow + row) * DD;
        __builtin_amdgcn_global_load_lds(
            (const __attribute__((address_space(1))) void*)ga,
            (__attribute__((address_space(3))) void*)((char*)(&As[buf][0]) + q * 4096 + tid * 16),
            16, 0, 0);
      }
      if (!diag) {
        #pragma unroll
        for (int q = 0; q < 2; ++q) {
          const int row = q * 64 + srow;
          const unsigned short* gb = base + (size_t)(bcol + row) * DD;
          __builtin_amdgcn_global_load_lds(
              (const __attribute__((address_space(1))) void*)gb,
              (__attribute__((address_space(3))) void*)((char*)(&Bs[buf][0]) + q * 4096 + tid * 16),
              16, 0, 0);
        }
      }
    } else {
      const float* base = dvec + (size_t)b * (NS * DD) + kk + scol;
      #pragma unroll
      for (int q = 0; q < 2; ++q) {
        const int row = q * 64 + srow;
        const float4* ga = reinterpret_cast<const float4*>(base + (size_t)(brow + row) * DD);
        float4 a0 = ga[0], a1 = ga[1];
        u16x8 pa;
        pa[0] = f2bf(a0.x); pa[1] = f2bf(a0.y); pa[2] = f2bf(a0.z); pa[3] = f2bf(a0.w);
        pa[4] = f2bf(a1.x); pa[5] = f2bf(a1.y); pa[6] = f2bf(a1.z); pa[7] = f2bf(a1.w);
        *reinterpret_cast<u16x8*>((char*)(&As[buf][0]) + q * 4096 + tid * 16) = pa;
      }
      if (!diag) {
        #pragma unroll
        for (int q = 0; q < 2; ++q) {
          const int row = q * 64 + srow;
          const float4* gb = reinterpret_cast<const float4*>(base + (size_t)(bcol + row) * DD);
          float4 c0 = gb[0], c1 = gb[1];
          u16x8 pb;
          pb[0] = f2bf(c0.x); pb[1] = f2bf(c0.y); pb[2] = f2bf(c0.z); pb[3] = f2bf(c0.w);
          pb[4] = f2bf(c1.x); pb[5] = f2bf(c1.y); pb[6] = f2bf(c1.z); pb[7] = f2bf(c1.w);
          *reinterpret_cast<u16x8*>((char*)(&Bs[buf][0]) + q * 4096 + tid * 16) = pb;
        }
      }
    }
  };

  STAGE(0, 0);
  __syncthreads();
  int cur = 0;

  // fragment reads: row = wbase + m*16 + (lane&15), data chunk cd = lane>>4
  // (k = cd*8 + i covers K=32). LDS chunk = cd ^ ((row>>1)&3) = cd ^ ((lane>>1)&3).
  // Bank pattern after swizzle: 2-way aliasing only (free, m136).
  const int xch = ((lane >> 4) ^ ((lane >> 1) & 3)) * 8;
  const int aoffs = (wr * 64 + (lane & 15)) * BK + xch;
  const int boffs = (wc * 64 + (lane & 15)) * BK + xch;
  const int NIT = GB * 8;

  for (int it = 0; it < NIT; ++it) {
    if (it + 1 < NIT) STAGE(cur ^ 1, it + 1);
    const unsigned short* Acur = &As[cur][0];
    const unsigned short* Bcur = diag ? &As[cur][0] : &Bs[cur][0];
    bf16x8 af[4], bfv[4];
    #pragma unroll
    for (int m = 0; m < 4; ++m)
      af[m] = *reinterpret_cast<const bf16x8*>(Acur + aoffs + m * 16 * BK);
    #pragma unroll
    for (int n = 0; n < 4; ++n)
      bfv[n] = *reinterpret_cast<const bf16x8*>(Bcur + boffs + n * 16 * BK);
    #pragma unroll
    for (int m = 0; m < 4; ++m)
      #pragma unroll
      for (int n = 0; n < 4; ++n)
        acc[m][n] = __builtin_amdgcn_mfma_f32_16x16x32_bf16(af[m], bfv[n], acc[m][n], 0, 0, 0);

    if ((it & 7) == 7) {
      // epilogue for batch b: only the (rare) kd-dependent terms.
      // pair (r,c), r<c: add kd^2*(W[r][c]+W[c][r]) - 2*kd*(W[r][c]S[r][c]+W[c][r]S[c][r])
      const int b = b0 + (it >> 3);
      const float* sqb = sq + (size_t)b * NS;
      const int hi = lane >> 4, lo = lane & 15;
      float lsum = 0.f;
      float sqc[4];
      #pragma unroll
      for (int n = 0; n < 4; ++n) sqc[n] = sqb[bcol + wc * 64 + n * 16 + lo];
      #pragma unroll
      for (int m = 0; m < 4; ++m) {
        #pragma unroll
        for (int j = 0; j < 4; ++j) {
          const int r = brow + wr * 64 + m * 16 + hi * 4 + j;
          const float sqr = sqb[r];
          #pragma unroll
          for (int n = 0; n < 4; ++n) {
            const int c = bcol + wc * 64 + n * 16 + lo;
            const float d2 = fmaxf(sqr + sqc[n] - 2.0f * acc[m][n][j], 0.0f);
            const bool hit = (r < c) && (d2 < THR);
            if (__any(hit)) {
              if (hit) {
                const float kd = __expf(-sqrtf(d2));
                const float wrc = W[(size_t)r * NS + c];
                const float wcr = W[(size_t)c * NS + r];
                const float src_ = S[(size_t)r * NS + c];
                const float scr = S[(size_t)c * NS + r];
                lsum = fmaf(kd, kd * (wrc + wcr) - 2.0f * fmaf(wrc, src_, wcr * scr), lsum);
              }
            }
          }
        }
      }
      if (__any(lsum != 0.f)) {
        #pragma unroll
        for (int off = 32; off > 0; off >>= 1) lsum += __shfl_xor(lsum, off, 64);
        if (lane == 0) atomicAdd(&numer2[b], lsum);
      }
      #pragma unroll
      for (int m = 0; m < 4; ++m)
        #pragma unroll
        for (int n = 0; n < 4; ++n) acc[m][n] = f32x4{0.f, 0.f, 0.f, 0.f};
    }
    __syncthreads();
    cur ^= 1;
  }
}

// ---- final: out = sum_b 2*sqrt(C + numer2[b]) / sqrt(denom2) ----
__global__ void final_kernel(const float* __restrict__ numer2,
                             const float* __restrict__ denom2,
                             const float* __restrict__ Cval,
                             float* __restrict__ out) {
  const int lane = threadIdx.x;
  float v = 2.0f * sqrtf(Cval[0] + numer2[lane]);
  #pragma unroll
  for (int off = 32; off > 0; off >>= 1) v += __shfl_xor(v, off, 64);
  if (lane == 0) out[0] = v / sqrtf(denom2[0]);
}

extern "C" void kernel_launch(void* const* d_in, const int* in_sizes, int n_in,
                              void* d_out, int out_size, void* d_ws, size_t ws_size,
                              hipStream_t stream) {
  const float* dvec = (const float*)d_in[0];
  const float* S = (const float*)d_in[1];
  const float* W = (const float*)d_in[2];
  float* out = (float*)d_out;

  const size_t bf_bytes = (size_t)NB * NS * DD * sizeof(unsigned short);  // 32 MiB
  const size_t sq_bytes = (size_t)NB * NS * sizeof(float);                // 256 KiB
  const size_t need_full = bf_bytes + sq_bytes + 66 * sizeof(float);
  const bool full = ws_size >= need_full;

  unsigned short* dbf;
  float* sqp;
  if (full) {
    dbf = (unsigned short*)d_ws;
    sqp = (float*)((char*)d_ws + bf_bytes);
  } else {
    dbf = nullptr;
    sqp = (float*)d_ws;
  }
  float* numer2 = sqp + (size_t)NB * NS;   // 64 floats
  float* denom2 = numer2 + NB;             // 1
  float* Cval = denom2 + 1;                // 1

  hipMemsetAsync(numer2, 0, 66 * sizeof(float), stream);
  prep_kernel<<<16384 + 1024, 256, 0, stream>>>(dvec, dbf, sqp, S, W, denom2, Cval,
                                                full ? 1 : 0);
  if (full)
    main_kernel<0><<<NT * (NB / GB), 256, 0, stream>>>(dvec, dbf, sqp, S, W, numer2);
  else
    main_kernel<1><<<NT * (NB / GB), 256, 0, stream>>>(dvec, dbf, sqp, S, W, numer2);
  final_kernel<<<1, 64, 0, stream>>>(numer2, denom2, Cval, out);
}

// Round 5
// 113.746 us; speedup vs baseline: 1.1083x; 1.1083x over previous
//
#include <hip/hip_runtime.h>
#include <hip/hip_bf16.h>

#define NB 64
#define NS 1024
#define DD 256
#define BM 128
#define BK 32
#define NT 36          // upper-triangular 8x8 tile count
#define GB 2           // batches per block
#define THR 120.0f     // dist^2 below which exp(-dist) can matter

typedef __attribute__((ext_vector_type(4))) float f32x4;
typedef __attribute__((ext_vector_type(8))) short bf16x8;
typedef __attribute__((ext_vector_type(8))) unsigned short u16x8;
typedef __attribute__((ext_vector_type(4))) unsigned short u16x4;

__device__ __forceinline__ unsigned short f2bf(float x) {
  union { float f; unsigned int u; } c; c.f = x;
  unsigned int r = c.u + 0x7fffu + ((c.u >> 16) & 1u);
  return (unsigned short)(r >> 16);
}

// ---- fused prep (sq + bf16 copy) and denom/C reduction ----
// blocks [0, 16384): prep rows; blocks [16384, 17408): denom + C
__global__ __launch_bounds__(256) void prep_kernel(const float* __restrict__ din,
                                                   unsigned short* __restrict__ dbf,
                                                   float* __restrict__ sq,
                                                   const float* __restrict__ S,
                                                   const float* __restrict__ W,
                                                   float* __restrict__ denom2,
                                                   float* __restrict__ Cval,
                                                   int write_bf) {
  if (blockIdx.x >= 16384) {
    const int t = ((int)blockIdx.x - 16384) * 256 + threadIdx.x;
    float4 w = reinterpret_cast<const float4*>(W)[t];
    float4 s = reinterpret_cast<const float4*>(S)[t];
    const int e0 = t << 2;
    const int r = e0 >> 10, c0 = e0 & 1023;
    float dsum = 0.f, csum = 0.f;
    float wv[4] = {w.x, w.y, w.z, w.w};
    float sv[4] = {s.x, s.y, s.z, s.w};
    #pragma unroll
    for (int i = 0; i < 4; ++i) {
      const bool dg = (c0 + i) == r;
      const float a = wv[i] - (dg ? 1.0f : 0.0f);
      dsum = fmaf(a, a, dsum);
      const float b = dg ? (1.0f - sv[i]) : sv[i];
      csum = fmaf(wv[i] * b, b, csum);   // W binary: W^2 == W
    }
    #pragma unroll
    for (int off = 32; off > 0; off >>= 1) {
      dsum += __shfl_xor(dsum, off, 64);
      csum += __shfl_xor(csum, off, 64);
    }
    __shared__ float redD[4], redC[4];
    if ((threadIdx.x & 63) == 0) { redD[threadIdx.x >> 6] = dsum; redC[threadIdx.x >> 6] = csum; }
    __syncthreads();
    if (threadIdx.x == 0) {
      atomicAdd(denom2, redD[0] + redD[1] + redD[2] + redD[3]);
      atomicAdd(Cval, redC[0] + redC[1] + redC[2] + redC[3]);
    }
    return;
  }
  const int row = blockIdx.x * 4 + (threadIdx.x >> 6);
  const int lane = threadIdx.x & 63;
  const float4* src = reinterpret_cast<const float4*>(din + (size_t)row * DD);
  float4 v = src[lane];
  float s = v.x * v.x + v.y * v.y + v.z * v.z + v.w * v.w;
  if (write_bf) {
    u16x4 o;
    o[0] = f2bf(v.x); o[1] = f2bf(v.y); o[2] = f2bf(v.z); o[3] = f2bf(v.w);
    reinterpret_cast<u16x4*>(dbf + (size_t)row * DD)[lane] = o;
  }
  #pragma unroll
  for (int off = 32; off > 0; off >>= 1) s += __shfl_xor(s, off, 64);
  if (lane == 0) sq[row] = s;
}

// ---- main: upper-triangular Gram tiles, MFMA, near-empty epilogue ----
// BK=32: LDS = 2buf x (A+B) x 8KB = 32KB -> 4 blocks/CU (LDS-limited) for
// latency overlap. launch_bounds(256,2): do NOT cap VGPR below the natural
// ~110 (R3's (256,4) forced 64 VGPR -> 70MB scratch spill, +20us).
// LDS tiles [128][32] bf16, 16B-chunk swizzle: data chunk cd of row r lives at
// LDS chunk cd ^ ((r>>1)&3). global_load_lds dest stays LINEAR; the inverse
// permutation is applied to the per-lane GLOBAL source (rule #21).
template <int MODE>
__global__ __launch_bounds__(256, 2) void main_kernel(
    const float* __restrict__ dvec, const unsigned short* __restrict__ dbf,
    const float* __restrict__ sq, const float* __restrict__ S,
    const float* __restrict__ W, float* __restrict__ numer2) {
  __shared__ unsigned short As[2][BM * BK];
  __shared__ unsigned short Bs[2][BM * BK];

  const int tid = threadIdx.x;
  const int lane = tid & 63;
  const int wid = tid >> 6;
  const int wr = wid >> 1;
  const int wc = wid & 1;

  // T1: XCD-chunked bijective swizzle (1152 = 8 * 144): each XCD owns 4
  // complete batch-groups -> panel set stays in its 4MB L2.
  const int orig = (int)blockIdx.x;
  const int bid = (orig & 7) * (NT * (NB / GB) / 8) + (orig >> 3);
  const int t = bid % NT;
  const int g = bid / NT;
  int u = t, ti = 0;
  while (u >= 8 - ti) { u -= 8 - ti; ++ti; }
  const int tj = ti + u;
  const int brow = ti * BM;
  const int bcol = tj * BM;
  const bool diag = (ti == tj);
  const int b0 = g * GB;

  // staging: thread writes LDS linear chunk (q*256 + tid) -> row = q*64 + (tid>>2),
  // lds chunk-in-row = tid&3. Source data chunk = (tid&3) ^ ((row>>1)&3)
  //   = (tid&3) ^ ((tid>>3)&3)   (q*64 rows -> (q*32)&3 == 0, q-independent)
  const int srow = tid >> 2;                                  // + q*64
  const int scol = (((tid & 3) ^ ((tid >> 3) & 3)) * 8);      // element offset

  f32x4 acc[4][4];
  #pragma unroll
  for (int m = 0; m < 4; ++m)
    #pragma unroll
    for (int n = 0; n < 4; ++n) acc[m][n] = f32x4{0.f, 0.f, 0.f, 0.f};

  auto STAGE = [&](int buf, int it) {
    const int b = b0 + (it >> 3);
    const int kk = (it & 7) * BK;
    if (MODE == 0) {
      const unsigned short* base = dbf + (size_t)b * (NS * DD) + kk + scol;
      #pragma unroll
      for (int q = 0; q < 2; ++q) {
        const int row = q * 64 + srow;
        const unsigned short* ga = base + (size_t)(brow + row) * DD;
        __builtin_amdgcn_global_load_lds(
            (const __attribute__((address_space(1))) void*)ga,
            (__attribute__((address_space(3))) void*)((char*)(&As[buf][0]) + q * 4096 + tid * 16),
            16, 0, 0);
      }
      if (!diag) {
        #pragma unroll
        for (int q = 0; q < 2; ++q) {
          const int row = q * 64 + srow;
          const unsigned short* gb = base + (size_t)(bcol + row) * DD;
          __builtin_amdgcn_global_load_lds(
              (const __attribute__((address_space(1))) void*)gb,
              (__attribute__((address_space(3))) void*)((char*)(&Bs[buf][0]) + q * 4096 + tid * 16),
              16, 0, 0);
        }
      }
    } else {
      const float* base = dvec + (size_t)b * (NS * DD) + kk + scol;
      #pragma unroll
      for (int q = 0; q < 2; ++q) {
        const int row = q * 64 + srow;
        const float4* ga = reinterpret_cast<const float4*>(base + (size_t)(brow + row) * DD);
        float4 a0 = ga[0], a1 = ga[1];
        u16x8 pa;
        pa[0] = f2bf(a0.x); pa[1] = f2bf(a0.y); pa[2] = f2bf(a0.z); pa[3] = f2bf(a0.w);
        pa[4] = f2bf(a1.x); pa[5] = f2bf(a1.y); pa[6] = f2bf(a1.z); pa[7] = f2bf(a1.w);
        *reinterpret_cast<u16x8*>((char*)(&As[buf][0]) + q * 4096 + tid * 16) = pa;
      }
      if (!diag) {
        #pragma unroll
        for (int q = 0; q < 2; ++q) {
          const int row = q * 64 + srow;
          const float4* gb = reinterpret_cast<const float4*>(base + (size_t)(bcol + row) * DD);
          float4 c0 = gb[0], c1 = gb[1];
          u16x8 pb;
          pb[0] = f2bf(c0.x); pb[1] = f2bf(c0.y); pb[2] = f2bf(c0.z); pb[3] = f2bf(c0.w);
          pb[4] = f2bf(c1.x); pb[5] = f2bf(c1.y); pb[6] = f2bf(c1.z); pb[7] = f2bf(c1.w);
          *reinterpret_cast<u16x8*>((char*)(&Bs[buf][0]) + q * 4096 + tid * 16) = pb;
        }
      }
    }
  };

  STAGE(0, 0);
  __syncthreads();
  int cur = 0;

  // fragment reads: row = wbase + m*16 + (lane&15), data chunk cd = lane>>4
  // (k = cd*8 + i covers K=32). LDS chunk = cd ^ ((row>>1)&3) = cd ^ ((lane>>1)&3).
  // Bank pattern after swizzle: 2-way aliasing only (free, m136).
  const int xch = ((lane >> 4) ^ ((lane >> 1) & 3)) * 8;
  const int aoffs = (wr * 64 + (lane & 15)) * BK + xch;
  const int boffs = (wc * 64 + (lane & 15)) * BK + xch;
  const int NIT = GB * 8;

  for (int it = 0; it < NIT; ++it) {
    if (it + 1 < NIT) STAGE(cur ^ 1, it + 1);
    const unsigned short* Acur = &As[cur][0];
    const unsigned short* Bcur = diag ? &As[cur][0] : &Bs[cur][0];
    bf16x8 af[4], bfv[4];
    #pragma unroll
    for (int m = 0; m < 4; ++m)
      af[m] = *reinterpret_cast<const bf16x8*>(Acur + aoffs + m * 16 * BK);
    #pragma unroll
    for (int n = 0; n < 4; ++n)
      bfv[n] = *reinterpret_cast<const bf16x8*>(Bcur + boffs + n * 16 * BK);
    #pragma unroll
    for (int m = 0; m < 4; ++m)
      #pragma unroll
      for (int n = 0; n < 4; ++n)
        acc[m][n] = __builtin_amdgcn_mfma_f32_16x16x32_bf16(af[m], bfv[n], acc[m][n], 0, 0, 0);

    if ((it & 7) == 7) {
      // epilogue for batch b: only the (rare) kd-dependent terms.
      // pair (r,c), r<c: add kd^2*(W[r][c]+W[c][r]) - 2*kd*(W[r][c]S[r][c]+W[c][r]S[c][r])
      const int b = b0 + (it >> 3);
      const float* sqb = sq + (size_t)b * NS;
      const int hi = lane >> 4, lo = lane & 15;
      float lsum = 0.f;
      float sqc[4];
      #pragma unroll
      for (int n = 0; n < 4; ++n) sqc[n] = sqb[bcol + wc * 64 + n * 16 + lo];
      #pragma unroll
      for (int m = 0; m < 4; ++m) {
        #pragma unroll
        for (int j = 0; j < 4; ++j) {
          const int r = brow + wr * 64 + m * 16 + hi * 4 + j;
          const float sqr = sqb[r];
          #pragma unroll
          for (int n = 0; n < 4; ++n) {
            const int c = bcol + wc * 64 + n * 16 + lo;
            const float d2 = fmaxf(sqr + sqc[n] - 2.0f * acc[m][n][j], 0.0f);
            const bool hit = (r < c) && (d2 < THR);
            if (__any(hit)) {
              if (hit) {
                const float kd = __expf(-sqrtf(d2));
                const float wrc = W[(size_t)r * NS + c];
                const float wcr = W[(size_t)c * NS + r];
                const float src_ = S[(size_t)r * NS + c];
                const float scr = S[(size_t)c * NS + r];
                lsum = fmaf(kd, kd * (wrc + wcr) - 2.0f * fmaf(wrc, src_, wcr * scr), lsum);
              }
            }
          }
        }
      }
      if (__any(lsum != 0.f)) {
        #pragma unroll
        for (int off = 32; off > 0; off >>= 1) lsum += __shfl_xor(lsum, off, 64);
        if (lane == 0) atomicAdd(&numer2[b], lsum);
      }
      #pragma unroll
      for (int m = 0; m < 4; ++m)
        #pragma unroll
        for (int n = 0; n < 4; ++n) acc[m][n] = f32x4{0.f, 0.f, 0.f, 0.f};
    }
    __syncthreads();
    cur ^= 1;
  }
}

// ---- final: out = sum_b 2*sqrt(C + numer2[b]) / sqrt(denom2) ----
__global__ void final_kernel(const float* __restrict__ numer2,
                             const float* __restrict__ denom2,
                             const float* __restrict__ Cval,
                             float* __restrict__ out) {
  const int lane = threadIdx.x;
  float v = 2.0f * sqrtf(Cval[0] + numer2[lane]);
  #pragma unroll
  for (int off = 32; off > 0; off >>= 1) v += __shfl_xor(v, off, 64);
  if (lane == 0) out[0] = v / sqrtf(denom2[0]);
}

extern "C" void kernel_launch(void* const* d_in, const int* in_sizes, int n_in,
                              void* d_out, int out_size, void* d_ws, size_t ws_size,
                              hipStream_t stream) {
  const float* dvec = (const float*)d_in[0];
  const float* S = (const float*)d_in[1];
  const float* W = (const float*)d_in[2];
  float* out = (float*)d_out;

  const size_t bf_bytes = (size_t)NB * NS * DD * sizeof(unsigned short);  // 32 MiB
  const size_t sq_bytes = (size_t)NB * NS * sizeof(float);                // 256 KiB
  const size_t need_full = bf_bytes + sq_bytes + 66 * sizeof(float);
  const bool full = ws_size >= need_full;

  unsigned short* dbf;
  float* sqp;
  if (full) {
    dbf = (unsigned short*)d_ws;
    sqp = (float*)((char*)d_ws + bf_bytes);
  } else {
    dbf = nullptr;
    sqp = (float*)d_ws;
  }
  float* numer2 = sqp + (size_t)NB * NS;   // 64 floats
  float* denom2 = numer2 + NB;             // 1
  float* Cval = denom2 + 1;                // 1

  hipMemsetAsync(numer2, 0, 66 * sizeof(float), stream);
  prep_kernel<<<16384 + 1024, 256, 0, stream>>>(dvec, dbf, sqp, S, W, denom2, Cval,
                                                full ? 1 : 0);
  if (full)
    main_kernel<0><<<NT * (NB / GB), 256, 0, stream>>>(dvec, dbf, sqp, S, W, numer2);
  else
    main_kernel<1><<<NT * (NB / GB), 256, 0, stream>>>(dvec, dbf, sqp, S, W, numer2);
  final_kernel<<<1, 64, 0, stream>>>(numer2, denom2, Cval, out);
}

// Round 6
// 111.132 us; speedup vs baseline: 1.1344x; 1.0235x over previous
//
#include <hip/hip_runtime.h>
#include <hip/hip_bf16.h>

#define NB 64
#define NS 1024
#define DD 256
#define NT 36          // upper-triangular 8x8 tile count
#define GB 2           // batches per block
#define THR 120.0f     // dist^2 below which exp(-dist) can matter

typedef __attribute__((ext_vector_type(4))) float f32x4;
typedef __attribute__((ext_vector_type(8))) short bf16x8;
typedef __attribute__((ext_vector_type(8))) unsigned short u16x8;

__device__ __forceinline__ unsigned short f2bf(float x) {
  union { float f; unsigned int u; } c; c.f = x;
  unsigned int r = c.u + 0x7fffu + ((c.u >> 16) & 1u);
  return (unsigned short)(r >> 16);
}

// dbf2 layout (fragment-major): block(b, rt, kg) = ((b*64 + rt)*8 + kg), 512
// bf16 each. Slot l (0..63) holds 8 bf16: row = rt*16 + (l&15),
// k = kg*32 + (l>>4)*8 + 0..7.  A wave's MFMA fragment load is then ONE
// fully-coalesced 1KB global_load_dwordx4 (lane l reads slot l).

// ---- prep: blocks [0,1024): per-wave (b, rt) transpose + sq (no atomics)
//      blocks [1024,1536): denom2 + C reduction over W/S ----
__global__ __launch_bounds__(256) void prep_kernel(const float* __restrict__ din,
                                                   unsigned short* __restrict__ dbf2,
                                                   float* __restrict__ sq,
                                                   const float* __restrict__ S,
                                                   const float* __restrict__ W,
                                                   float* __restrict__ denom2,
                                                   float* __restrict__ Cval,
                                                   int write_bf) {
  const int bx = (int)blockIdx.x;
  if (bx < 1024) {
    const int task = bx * 4 + ((int)threadIdx.x >> 6);  // (b,rt): b*64+rt
    const int b = task >> 6, rt = task & 63;
    const int l = threadIdx.x & 63;
    const int lr = l & 15;              // row within 16-row tile
    const int kb = (l >> 4) * 64;       // this lane's quarter of k-range
    const float* src = din + ((size_t)b * NS + rt * 16 + lr) * DD + kb;
    float s = 0.f;
    u16x8 stash;
    #pragma unroll
    for (int c = 0; c < 16; ++c) {
      float4 v = reinterpret_cast<const float4*>(src)[c];
      s += v.x * v.x + v.y * v.y + v.z * v.z + v.w * v.w;
      const int h = (c & 1) * 4;
      stash[h + 0] = f2bf(v.x); stash[h + 1] = f2bf(v.y);
      stash[h + 2] = f2bf(v.z); stash[h + 3] = f2bf(v.w);
      if ((c & 1) && write_bf) {
        const int kp = kb + (c >> 1) * 8;
        const int kg = kp >> 5;
        const int k8 = (kp & 31) >> 3;
        // write 16B to slot (k8*16 + lr) of block (b,rt,kg): 16 lanes of the
        // same k8 are contiguous 256B runs -> good store coalescing.
        *reinterpret_cast<u16x8*>(
            dbf2 + (((size_t)(b * 64 + rt) * 8 + kg) * 64 + k8 * 16 + lr) * 8) = stash;
      }
    }
    s += __shfl_xor(s, 16, 64);
    s += __shfl_xor(s, 32, 64);
    if (l < 16) sq[(size_t)b * NS + rt * 16 + l] = s;
    return;
  }
  // denomC over W,S (1M floats each = 262144 float4): 512 blocks x 256 thr x 2
  const int base = (bx - 1024) * 256 + (int)threadIdx.x;
  float dsum = 0.f, csum = 0.f;
  #pragma unroll
  for (int rpt = 0; rpt < 2; ++rpt) {
    const int idx = base + rpt * 131072;
    float4 w = reinterpret_cast<const float4*>(W)[idx];
    float4 s4 = reinterpret_cast<const float4*>(S)[idx];
    const int e0 = idx << 2;
    const int r = e0 >> 10, c0 = e0 & 1023;
    float wv[4] = {w.x, w.y, w.z, w.w};
    float sv[4] = {s4.x, s4.y, s4.z, s4.w};
    #pragma unroll
    for (int i = 0; i < 4; ++i) {
      const bool dg = (c0 + i) == r;
      const float a = wv[i] - (dg ? 1.0f : 0.0f);
      dsum = fmaf(a, a, dsum);
      const float bq = dg ? (1.0f - sv[i]) : sv[i];
      csum = fmaf(wv[i] * bq, bq, csum);   // W binary: W^2 == W
    }
  }
  #pragma unroll
  for (int off = 32; off > 0; off >>= 1) {
    dsum += __shfl_xor(dsum, off, 64);
    csum += __shfl_xor(csum, off, 64);
  }
  __shared__ float redD[4], redC[4];
  if ((threadIdx.x & 63) == 0) { redD[threadIdx.x >> 6] = dsum; redC[threadIdx.x >> 6] = csum; }
  __syncthreads();
  if (threadIdx.x == 0) {
    atomicAdd(denom2, redD[0] + redD[1] + redD[2] + redD[3]);
    atomicAdd(Cval, redC[0] + redC[1] + redC[2] + redC[3]);
  }
}

// ---- main: barrier-free, LDS-free MFMA Gram over upper-triangular tiles ----
// Each wave owns a 64x64 sub-tile; fragments load straight from L2-resident
// dbf2 (MODE 0: one coalesced 1KB load per fragment) into VGPRs. No
// __syncthreads anywhere -> no vmcnt(0) drains; compiler pipelines freely.
// MODE 1 fallback: read f32 dvec directly, cvt in-register.
template <int MODE>
__global__ __launch_bounds__(256, 2) void main_kernel(
    const float* __restrict__ dvec, const unsigned short* __restrict__ dbf2,
    const float* __restrict__ sq, const float* __restrict__ S,
    const float* __restrict__ W, float* __restrict__ numer2) {
  const int tid = threadIdx.x;
  const int lane = tid & 63;
  const int wid = tid >> 6;
  const int wr = wid >> 1;
  const int wc = wid & 1;

  // T1: XCD-chunked bijective swizzle (1152 = 8 * 144): each XCD owns 4
  // complete batch-groups -> its panel set stays in the 4MB L2.
  const int orig = (int)blockIdx.x;
  const int bid = (orig & 7) * (NT * (NB / GB) / 8) + (orig >> 3);
  const int t = bid % NT;
  const int g = bid / NT;
  int u = t, ti = 0;
  while (u >= 8 - ti) { u -= 8 - ti; ++ti; }
  const int tj = ti + u;
  const int brow = ti * 128;
  const int bcol = tj * 128;
  const int b0 = g * GB;

  const int rtA0 = ti * 8 + wr * 4;   // A row-tiles (of 16 rows) for this wave
  const int rtB0 = tj * 8 + wc * 4;   // B row-tiles (Gram columns)

  for (int bb = 0; bb < GB; ++bb) {
    const int b = b0 + bb;
    f32x4 acc[4][4];
    #pragma unroll
    for (int m = 0; m < 4; ++m)
      #pragma unroll
      for (int n = 0; n < 4; ++n) acc[m][n] = f32x4{0.f, 0.f, 0.f, 0.f};

    if (MODE == 0) {
      const unsigned short* fb = dbf2 + (size_t)b * (64 * 8 * 512) + (size_t)lane * 8;
      #pragma unroll
      for (int kg = 0; kg < 8; ++kg) {
        bf16x8 af[4], bf[4];
        #pragma unroll
        for (int m = 0; m < 4; ++m)
          af[m] = *reinterpret_cast<const bf16x8*>(fb + ((size_t)(rtA0 + m) * 8 + kg) * 512);
        #pragma unroll
        for (int n = 0; n < 4; ++n)
          bf[n] = *reinterpret_cast<const bf16x8*>(fb + ((size_t)(rtB0 + n) * 8 + kg) * 512);
        #pragma unroll
        for (int m = 0; m < 4; ++m)
          #pragma unroll
          for (int n = 0; n < 4; ++n)
            acc[m][n] = __builtin_amdgcn_mfma_f32_16x16x32_bf16(af[m], bf[n], acc[m][n], 0, 0, 0);
      }
    } else {
      const float* pbase = dvec + (size_t)b * NS * DD + (lane >> 4) * 8;
      #pragma unroll
      for (int kg = 0; kg < 8; ++kg) {
        bf16x8 af[4], bf[4];
        #pragma unroll
        for (int m = 0; m < 4; ++m) {
          const float* p = pbase + (size_t)((rtA0 + m) * 16 + (lane & 15)) * DD + kg * 32;
          float4 v0 = reinterpret_cast<const float4*>(p)[0];
          float4 v1 = reinterpret_cast<const float4*>(p)[1];
          af[m][0] = (short)f2bf(v0.x); af[m][1] = (short)f2bf(v0.y);
          af[m][2] = (short)f2bf(v0.z); af[m][3] = (short)f2bf(v0.w);
          af[m][4] = (short)f2bf(v1.x); af[m][5] = (short)f2bf(v1.y);
          af[m][6] = (short)f2bf(v1.z); af[m][7] = (short)f2bf(v1.w);
        }
        #pragma unroll
        for (int n = 0; n < 4; ++n) {
          const float* p = pbase + (size_t)((rtB0 + n) * 16 + (lane & 15)) * DD + kg * 32;
          float4 v0 = reinterpret_cast<const float4*>(p)[0];
          float4 v1 = reinterpret_cast<const float4*>(p)[1];
          bf[n][0] = (short)f2bf(v0.x); bf[n][1] = (short)f2bf(v0.y);
          bf[n][2] = (short)f2bf(v0.z); bf[n][3] = (short)f2bf(v0.w);
          bf[n][4] = (short)f2bf(v1.x); bf[n][5] = (short)f2bf(v1.y);
          bf[n][6] = (short)f2bf(v1.z); bf[n][7] = (short)f2bf(v1.w);
        }
        #pragma unroll
        for (int m = 0; m < 4; ++m)
          #pragma unroll
          for (int n = 0; n < 4; ++n)
            acc[m][n] = __builtin_amdgcn_mfma_f32_16x16x32_bf16(af[m], bf[n], acc[m][n], 0, 0, 0);
      }
    }

    // epilogue: only the (rare) kd-dependent terms survive the algebra.
    // pair (r,c), r<c: add kd^2*(W[r][c]+W[c][r]) - 2*kd*(W[r][c]S[r][c]+W[c][r]S[c][r])
    const float* sqb = sq + (size_t)b * NS;
    const int hi = lane >> 4, lo = lane & 15;
    float lsum = 0.f;
    float sqc[4];
    #pragma unroll
    for (int n = 0; n < 4; ++n) sqc[n] = sqb[bcol + wc * 64 + n * 16 + lo];
    #pragma unroll
    for (int m = 0; m < 4; ++m) {
      #pragma unroll
      for (int j = 0; j < 4; ++j) {
        const int r = brow + wr * 64 + m * 16 + hi * 4 + j;
        const float sqr = sqb[r];
        #pragma unroll
        for (int n = 0; n < 4; ++n) {
          const int c = bcol + wc * 64 + n * 16 + lo;
          const float d2 = fmaxf(sqr + sqc[n] - 2.0f * acc[m][n][j], 0.0f);
          const bool hit = (r < c) && (d2 < THR);
          if (__any(hit)) {
            if (hit) {
              const float kd = __expf(-sqrtf(d2));
              const float wrc = W[(size_t)r * NS + c];
              const float wcr = W[(size_t)c * NS + r];
              const float src_ = S[(size_t)r * NS + c];
              const float scr = S[(size_t)c * NS + r];
              lsum = fmaf(kd, kd * (wrc + wcr) - 2.0f * fmaf(wrc, src_, wcr * scr), lsum);
            }
          }
        }
      }
    }
    if (__any(lsum != 0.f)) {
      #pragma unroll
      for (int off = 32; off > 0; off >>= 1) lsum += __shfl_xor(lsum, off, 64);
      if (lane == 0) atomicAdd(&numer2[b], lsum);
    }
  }
}

// ---- final: out = sum_b 2*sqrt(C + numer2[b]) / sqrt(denom2) ----
__global__ void final_kernel(const float* __restrict__ numer2,
                             const float* __restrict__ denom2,
                             const float* __restrict__ Cval,
                             float* __restrict__ out) {
  const int lane = threadIdx.x;
  float v = 2.0f * sqrtf(Cval[0] + numer2[lane]);
  #pragma unroll
  for (int off = 32; off > 0; off >>= 1) v += __shfl_xor(v, off, 64);
  if (lane == 0) out[0] = v / sqrtf(denom2[0]);
}

extern "C" void kernel_launch(void* const* d_in, const int* in_sizes, int n_in,
                              void* d_out, int out_size, void* d_ws, size_t ws_size,
                              hipStream_t stream) {
  const float* dvec = (const float*)d_in[0];
  const float* S = (const float*)d_in[1];
  const float* W = (const float*)d_in[2];
  float* out = (float*)d_out;

  const size_t bf_bytes = (size_t)NB * NS * DD * sizeof(unsigned short);  // 32 MiB
  const size_t sq_bytes = (size_t)NB * NS * sizeof(float);                // 256 KiB
  const size_t need_full = bf_bytes + sq_bytes + 66 * sizeof(float);
  const bool full = ws_size >= need_full;

  unsigned short* dbf2;
  float* sqp;
  if (full) {
    dbf2 = (unsigned short*)d_ws;
    sqp = (float*)((char*)d_ws + bf_bytes);
  } else {
    dbf2 = nullptr;
    sqp = (float*)d_ws;
  }
  float* numer2 = sqp + (size_t)NB * NS;   // 64 floats
  float* denom2 = numer2 + NB;             // 1
  float* Cval = denom2 + 1;                // 1

  hipMemsetAsync(numer2, 0, 66 * sizeof(float), stream);
  prep_kernel<<<1536, 256, 0, stream>>>(dvec, dbf2, sqp, S, W, denom2, Cval,
                                        full ? 1 : 0);
  if (full)
    main_kernel<0><<<NT * (NB / GB), 256, 0, stream>>>(dvec, dbf2, sqp, S, W, numer2);
  else
    main_kernel<1><<<NT * (NB / GB), 256, 0, stream>>>(dvec, dbf2, sqp, S, W, numer2);
  final_kernel<<<1, 64, 0, stream>>>(numer2, denom2, Cval, out);
}

// Round 7
// 69.656 us; speedup vs baseline: 1.8099x; 1.5954x over previous
//
#include <hip/hip_runtime.h>
#include <hip/hip_bf16.h>

#define NB 64
#define NS 1024
#define DD 256
#define NT 36          // upper-triangular 8x8 tile count
#define THR 120.0f     // dist^2 below which exp(-dist) can matter

typedef __attribute__((ext_vector_type(4))) float f32x4;
typedef __attribute__((ext_vector_type(8))) short bf16x8;
typedef __attribute__((ext_vector_type(8))) unsigned short u16x8;

__device__ __forceinline__ unsigned short f2bf(float x) {
  union { float f; unsigned int u; } c; c.f = x;
  unsigned int r = c.u + 0x7fffu + ((c.u >> 16) & 1u);
  return (unsigned short)(r >> 16);
}

// dbf2 layout (kg-major fragment blocks): block(b, kg, rt) = (b*8 + kg)*64 + rt,
// 512 bf16 each. Slot l (0..63) holds 8 bf16: row = rt*16 + (l&15),
// k = kg*32 + (l>>4)*8 + 0..7.  A wave's MFMA fragment load is ONE coalesced
// 1KB global_load_dwordx4; consecutive m are +1024B immediates.

// ---- prep: blocks [0,1024): per-wave (b,rt) transpose+sq, XCD-matched so the
//      XCD that writes batch b is the one that reads it in main_kernel.
//      blocks [1024,1536): denom2 + C reduction over W/S ----
__global__ __launch_bounds__(256) void prep_kernel(const float* __restrict__ din,
                                                   unsigned short* __restrict__ dbf2,
                                                   float* __restrict__ sq,
                                                   const float* __restrict__ S,
                                                   const float* __restrict__ W,
                                                   float* __restrict__ denom2,
                                                   float* __restrict__ Cval,
                                                   int write_bf) {
  const int px = (int)blockIdx.x;
  if (px < 1024) {
    // XCD k (= px&7, round-robin dispatch) handles tb in [128k,128k+128)
    //  -> tasks [512k, 512k+512) -> b in [8k, 8k+8): matches main's consumer XCD.
    const int tb = (px & 7) * 128 + (px >> 3);
    const int task = tb * 4 + ((int)threadIdx.x >> 6);  // b*64 + rt
    const int b = task >> 6, rt = task & 63;
    const int l = threadIdx.x & 63;
    const int lr = l & 15;              // row within 16-row tile
    const int kb = (l >> 4) * 64;       // this lane's quarter of k-range
    const float* src = din + ((size_t)b * NS + rt * 16 + lr) * DD + kb;
    float s = 0.f;
    u16x8 stash;
    #pragma unroll
    for (int c = 0; c < 16; ++c) {
      float4 v = reinterpret_cast<const float4*>(src)[c];
      s += v.x * v.x + v.y * v.y + v.z * v.z + v.w * v.w;
      const int h = (c & 1) * 4;
      stash[h + 0] = f2bf(v.x); stash[h + 1] = f2bf(v.y);
      stash[h + 2] = f2bf(v.z); stash[h + 3] = f2bf(v.w);
      if ((c & 1) && write_bf) {
        const int kp = kb + (c >> 1) * 8;
        const int kg = kp >> 5;
        const int k8 = (kp & 31) >> 3;
        *reinterpret_cast<u16x8*>(
            dbf2 + ((((size_t)b * 8 + kg) * 64 + rt) * 64 + k8 * 16 + lr) * 8) = stash;
      }
    }
    s += __shfl_xor(s, 16, 64);
    s += __shfl_xor(s, 32, 64);
    if (l < 16) sq[(size_t)b * NS + rt * 16 + l] = s;
    return;
  }
  // denomC over W,S: 512 blocks x 256 thr x 2 float4
  const int base = (px - 1024) * 256 + (int)threadIdx.x;
  float dsum = 0.f, csum = 0.f;
  #pragma unroll
  for (int rpt = 0; rpt < 2; ++rpt) {
    const int idx = base + rpt * 131072;
    float4 w = reinterpret_cast<const float4*>(W)[idx];
    float4 s4 = reinterpret_cast<const float4*>(S)[idx];
    const int e0 = idx << 2;
    const int r = e0 >> 10, c0 = e0 & 1023;
    float wv[4] = {w.x, w.y, w.z, w.w};
    float sv[4] = {s4.x, s4.y, s4.z, s4.w};
    #pragma unroll
    for (int i = 0; i < 4; ++i) {
      const bool dg = (c0 + i) == r;
      const float a = wv[i] - (dg ? 1.0f : 0.0f);
      dsum = fmaf(a, a, dsum);
      const float bq = dg ? (1.0f - sv[i]) : sv[i];
      csum = fmaf(wv[i] * bq, bq, csum);   // W binary: W^2 == W
    }
  }
  #pragma unroll
  for (int off = 32; off > 0; off >>= 1) {
    dsum += __shfl_xor(dsum, off, 64);
    csum += __shfl_xor(csum, off, 64);
  }
  __shared__ float redD[4], redC[4];
  if ((threadIdx.x & 63) == 0) { redD[threadIdx.x >> 6] = dsum; redC[threadIdx.x >> 6] = csum; }
  __syncthreads();
  if (threadIdx.x == 0) {
    atomicAdd(denom2, redD[0] + redD[1] + redD[2] + redD[3]);
    atomicAdd(Cval, redC[0] + redC[1] + redC[2] + redC[3]);
  }
}

// ---- main: barrier-free LDS-free MFMA Gram; one batch per block (GB=1).
// Fragment loads hit the LOCAL XCD L2 (prep placement matched). Software
// prefetch distance 1: A(kg+1) into nf[] before MFMAs; B(kg+1) reloaded right
// after each bf[n]'s last use, so loads overlap the MFMA cluster.
template <int MODE>
__global__ __launch_bounds__(256, 2) void main_kernel(
    const float* __restrict__ dvec, const unsigned short* __restrict__ dbf2,
    const float* __restrict__ sq, const float* __restrict__ S,
    const float* __restrict__ W, float* __restrict__ numer2) {
  const int tid = threadIdx.x;
  const int lane = tid & 63;
  const int wid = tid >> 6;
  const int wr = wid >> 1;
  const int wc = wid & 1;

  // XCD-chunked bijective swizzle (2304 = 8 * 288): XCD k gets bids
  // [288k, 288k+288) -> b in [8k, 8k+8) (t-fast) = the batches its L2 holds.
  const int orig = (int)blockIdx.x;
  const int bid = (orig & 7) * (NT * NB / 8) + (orig >> 3);
  const int t = bid % NT;
  const int b = bid / NT;
  int u = t, ti = 0;
  while (u >= 8 - ti) { u -= 8 - ti; ++ti; }
  const int tj = ti + u;
  const int brow = ti * 128;
  const int bcol = tj * 128;

  const int rtA0 = ti * 8 + wr * 4;   // A row-tiles (16 rows each)
  const int rtB0 = tj * 8 + wc * 4;   // B row-tiles (Gram columns)

  f32x4 acc[4][4];
  #pragma unroll
  for (int m = 0; m < 4; ++m)
    #pragma unroll
    for (int n = 0; n < 4; ++n) acc[m][n] = f32x4{0.f, 0.f, 0.f, 0.f};

  if (MODE == 0) {
    const unsigned short* pa =
        dbf2 + (((size_t)b * 8) * 64 + rtA0) * 512 + (size_t)lane * 8;
    const unsigned short* pb =
        dbf2 + (((size_t)b * 8) * 64 + rtB0) * 512 + (size_t)lane * 8;
    bf16x8 af[4], bf[4], nf[4];
    #pragma unroll
    for (int m = 0; m < 4; ++m)
      af[m] = *reinterpret_cast<const bf16x8*>(pa + m * 512);
    #pragma unroll
    for (int n = 0; n < 4; ++n)
      bf[n] = *reinterpret_cast<const bf16x8*>(pb + n * 512);
    #pragma unroll
    for (int kg = 0; kg < 8; ++kg) {
      if (kg < 7) {
        #pragma unroll
        for (int m = 0; m < 4; ++m)
          nf[m] = *reinterpret_cast<const bf16x8*>(pa + 32768 + m * 512);
      }
      #pragma unroll
      for (int n = 0; n < 4; ++n) {
        #pragma unroll
        for (int m = 0; m < 4; ++m)
          acc[m][n] = __builtin_amdgcn_mfma_f32_16x16x32_bf16(af[m], bf[n], acc[m][n], 0, 0, 0);
        if (kg < 7)
          bf[n] = *reinterpret_cast<const bf16x8*>(pb + 32768 + n * 512);  // bf[n] dead
      }
      if (kg < 7) {
        #pragma unroll
        for (int m = 0; m < 4; ++m) af[m] = nf[m];
        pa += 32768; pb += 32768;
      }
    }
  } else {
    const float* pbase = dvec + (size_t)b * NS * DD + (lane >> 4) * 8;
    #pragma unroll
    for (int kg = 0; kg < 8; ++kg) {
      bf16x8 af[4], bf[4];
      #pragma unroll
      for (int m = 0; m < 4; ++m) {
        const float* p = pbase + (size_t)((rtA0 + m) * 16 + (lane & 15)) * DD + kg * 32;
        float4 v0 = reinterpret_cast<const float4*>(p)[0];
        float4 v1 = reinterpret_cast<const float4*>(p)[1];
        af[m][0] = (short)f2bf(v0.x); af[m][1] = (short)f2bf(v0.y);
        af[m][2] = (short)f2bf(v0.z); af[m][3] = (short)f2bf(v0.w);
        af[m][4] = (short)f2bf(v1.x); af[m][5] = (short)f2bf(v1.y);
        af[m][6] = (short)f2bf(v1.z); af[m][7] = (short)f2bf(v1.w);
      }
      #pragma unroll
      for (int n = 0; n < 4; ++n) {
        const float* p = pbase + (size_t)((rtB0 + n) * 16 + (lane & 15)) * DD + kg * 32;
        float4 v0 = reinterpret_cast<const float4*>(p)[0];
        float4 v1 = reinterpret_cast<const float4*>(p)[1];
        bf[n][0] = (short)f2bf(v0.x); bf[n][1] = (short)f2bf(v0.y);
        bf[n][2] = (short)f2bf(v0.z); bf[n][3] = (short)f2bf(v0.w);
        bf[n][4] = (short)f2bf(v1.x); bf[n][5] = (short)f2bf(v1.y);
        bf[n][6] = (short)f2bf(v1.z); bf[n][7] = (short)f2bf(v1.w);
      }
      #pragma unroll
      for (int m = 0; m < 4; ++m)
        #pragma unroll
        for (int n = 0; n < 4; ++n)
          acc[m][n] = __builtin_amdgcn_mfma_f32_16x16x32_bf16(af[m], bf[n], acc[m][n], 0, 0, 0);
    }
  }

  // ---- epilogue, two-pass. pass 1: branch-free min scan of d2 over this
  // wave's 64x64 sub-tile (upper-triangular elements only). The kd terms
  // matter only when d2 < THR (exp(-dist) sub-eps otherwise; bit-identical
  // result in f32) -> common case is ONE ballot, no branches.
  const float* sqb = sq + (size_t)b * NS;
  const int hi = lane >> 4, lo = lane & 15;
  float sqc[4];
  #pragma unroll
  for (int n = 0; n < 4; ++n) sqc[n] = sqb[bcol + wc * 64 + n * 16 + lo];
  float dmin = 1e30f;
  #pragma unroll
  for (int m = 0; m < 4; ++m) {
    #pragma unroll
    for (int j = 0; j < 4; ++j) {
      const int r = brow + wr * 64 + m * 16 + hi * 4 + j;
      const float sqr = sqb[r];
      #pragma unroll
      for (int n = 0; n < 4; ++n) {
        const int c = bcol + wc * 64 + n * 16 + lo;
        const float d2 = fmaxf(sqr + sqc[n] - 2.0f * acc[m][n][j], 0.0f);
        dmin = fminf(dmin, (r < c) ? d2 : 1e30f);
      }
    }
  }
  if (__any(dmin < THR)) {
    // rare path: pair (r,c), r<c:
    //   add kd^2*(W[r][c]+W[c][r]) - 2*kd*(W[r][c]S[r][c]+W[c][r]S[c][r])
    float lsum = 0.f;
    #pragma unroll
    for (int m = 0; m < 4; ++m) {
      #pragma unroll
      for (int j = 0; j < 4; ++j) {
        const int r = brow + wr * 64 + m * 16 + hi * 4 + j;
        const float sqr = sqb[r];
        #pragma unroll
        for (int n = 0; n < 4; ++n) {
          const int c = bcol + wc * 64 + n * 16 + lo;
          const float d2 = fmaxf(sqr + sqc[n] - 2.0f * acc[m][n][j], 0.0f);
          if ((r < c) && (d2 < THR)) {
            const float kd = __expf(-sqrtf(d2));
            const float wrc = W[(size_t)r * NS + c];
            const float wcr = W[(size_t)c * NS + r];
            const float src_ = S[(size_t)r * NS + c];
            const float scr = S[(size_t)c * NS + r];
            lsum = fmaf(kd, kd * (wrc + wcr) - 2.0f * fmaf(wrc, src_, wcr * scr), lsum);
          }
        }
      }
    }
    #pragma unroll
    for (int off = 32; off > 0; off >>= 1) lsum += __shfl_xor(lsum, off, 64);
    if (lane == 0 && lsum != 0.f) atomicAdd(&numer2[b], lsum);
  }
}

// ---- final: out = sum_b 2*sqrt(C + numer2[b]) / sqrt(denom2) ----
__global__ void final_kernel(const float* __restrict__ numer2,
                             const float* __restrict__ denom2,
                             const float* __restrict__ Cval,
                             float* __restrict__ out) {
  const int lane = threadIdx.x;
  float v = 2.0f * sqrtf(Cval[0] + numer2[lane]);
  #pragma unroll
  for (int off = 32; off > 0; off >>= 1) v += __shfl_xor(v, off, 64);
  if (lane == 0) out[0] = v / sqrtf(denom2[0]);
}

extern "C" void kernel_launch(void* const* d_in, const int* in_sizes, int n_in,
                              void* d_out, int out_size, void* d_ws, size_t ws_size,
                              hipStream_t stream) {
  const float* dvec = (const float*)d_in[0];
  const float* S = (const float*)d_in[1];
  const float* W = (const float*)d_in[2];
  float* out = (float*)d_out;

  const size_t bf_bytes = (size_t)NB * NS * DD * sizeof(unsigned short);  // 32 MiB
  const size_t sq_bytes = (size_t)NB * NS * sizeof(float);                // 256 KiB
  const size_t need_full = bf_bytes + sq_bytes + 66 * sizeof(float);
  const bool full = ws_size >= need_full;

  unsigned short* dbf2;
  float* sqp;
  if (full) {
    dbf2 = (unsigned short*)d_ws;
    sqp = (float*)((char*)d_ws + bf_bytes);
  } else {
    dbf2 = nullptr;
    sqp = (float*)d_ws;
  }
  float* numer2 = sqp + (size_t)NB * NS;   // 64 floats
  float* denom2 = numer2 + NB;             // 1
  float* Cval = denom2 + 1;                // 1

  hipMemsetAsync(numer2, 0, 66 * sizeof(float), stream);
  prep_kernel<<<1536, 256, 0, stream>>>(dvec, dbf2, sqp, S, W, denom2, Cval,
                                        full ? 1 : 0);
  if (full)
    main_kernel<0><<<NT * NB, 256, 0, stream>>>(dvec, dbf2, sqp, S, W, numer2);
  else
    main_kernel<1><<<NT * NB, 256, 0, stream>>>(dvec, dbf2, sqp, S, W, numer2);
  final_kernel<<<1, 64, 0, stream>>>(numer2, denom2, Cval, out);
}

// Round 8
// 52.938 us; speedup vs baseline: 2.3814x; 1.3158x over previous
//
#include <hip/hip_runtime.h>
#include <hip/hip_bf16.h>

#define NB 64
#define NS 1024
#define DD 256
#define NT 36          // upper-triangular 8x8 tile count
#define THR 120.0f     // dist^2 below which exp(-dist) can matter

typedef __attribute__((ext_vector_type(4))) float f32x4;
typedef __attribute__((ext_vector_type(8))) short bf16x8;
typedef __attribute__((ext_vector_type(8))) unsigned short u16x8;
typedef __attribute__((ext_vector_type(4))) unsigned short u16x4;

__device__ __forceinline__ unsigned short f2bf(float x) {
  union { float f; unsigned int u; } c; c.f = x;
  unsigned int r = c.u + 0x7fffu + ((c.u >> 16) & 1u);
  return (unsigned short)(r >> 16);
}

// dbf2 layout (kg-major fragment blocks): block(b, kg, rt) = (b*8 + kg)*64 + rt,
// 512 bf16 each. Slot s (0..63) holds 8 bf16: row = rt*16 + (s&15),
// k = kg*32 + (s>>4)*8 + 0..7.  A wave's MFMA fragment load is ONE coalesced
// 1KB global_load_dwordx4.

// ---- prep: blocks [0,4096): one ROW per wave-iteration (fully coalesced 1KB
//      loads), sq via shuffle reduce, 8B/lane fragment scatter-store.
//      XCD-matched: XCD k (= px&7) handles batches [8k, 8k+8) = main's readers.
//      blocks [4096,4608): denom2/C partials over W/S (no atomics). ----
__global__ __launch_bounds__(256) void prep_kernel(const float* __restrict__ din,
                                                   unsigned short* __restrict__ dbf2,
                                                   float* __restrict__ sq,
                                                   const float* __restrict__ S,
                                                   const float* __restrict__ W,
                                                   float* __restrict__ dpart,
                                                   float* __restrict__ cpart,
                                                   int write_bf) {
  const int px = (int)blockIdx.x;
  const int wid = (int)threadIdx.x >> 6;
  const int l = (int)threadIdx.x & 63;
  if (px < 4096) {
    // rows: XCD k owns rows [k*8192, k*8192+8192) (= batches 8k..8k+8)
    const int rowbase = (px & 7) * 8192 + (px >> 3) * 16 + wid * 4;
    // lane l: floats 4l..4l+3 of the row -> kg = l>>3, k8 = (l>>1)&3, h = l&1
    const int kg = l >> 3, k8 = (l >> 1) & 3, h = l & 1;
    #pragma unroll
    for (int i = 0; i < 4; ++i) {
      const int r = rowbase + i;
      const int b = r >> 10, rr = r & 1023;
      const int rt = rr >> 4, lr = rr & 15;
      const float4 v = reinterpret_cast<const float4*>(din + (size_t)r * DD)[l];
      float s = v.x * v.x + v.y * v.y + v.z * v.z + v.w * v.w;
      #pragma unroll
      for (int off = 32; off > 0; off >>= 1) s += __shfl_xor(s, off, 64);
      if (l == 0) sq[r] = s;
      if (write_bf) {
        u16x4 o;
        o[0] = f2bf(v.x); o[1] = f2bf(v.y); o[2] = f2bf(v.z); o[3] = f2bf(v.w);
        *reinterpret_cast<u16x4*>(
            dbf2 + ((((size_t)b * 8 + kg) * 64 + rt) * 64 + k8 * 16 + lr) * 8 + h * 4) = o;
      }
    }
    return;
  }
  // denomC partials: blk in [0,512), 256 thr x 2 float4 each
  const int blk = px - 4096;
  const int base = blk * 256 + (int)threadIdx.x;
  float dsum = 0.f, csum = 0.f;
  #pragma unroll
  for (int rpt = 0; rpt < 2; ++rpt) {
    const int idx = base + rpt * 131072;
    float4 w = reinterpret_cast<const float4*>(W)[idx];
    float4 s4 = reinterpret_cast<const float4*>(S)[idx];
    const int e0 = idx << 2;
    const int r = e0 >> 10, c0 = e0 & 1023;
    float wv[4] = {w.x, w.y, w.z, w.w};
    float sv[4] = {s4.x, s4.y, s4.z, s4.w};
    #pragma unroll
    for (int i = 0; i < 4; ++i) {
      const bool dg = (c0 + i) == r;
      const float a = wv[i] - (dg ? 1.0f : 0.0f);
      dsum = fmaf(a, a, dsum);
      const float bq = dg ? (1.0f - sv[i]) : sv[i];
      csum = fmaf(wv[i] * bq, bq, csum);   // W binary: W^2 == W
    }
  }
  #pragma unroll
  for (int off = 32; off > 0; off >>= 1) {
    dsum += __shfl_xor(dsum, off, 64);
    csum += __shfl_xor(csum, off, 64);
  }
  __shared__ float redD[4], redC[4];
  if (l == 0) { redD[wid] = dsum; redC[wid] = csum; }
  __syncthreads();
  if (threadIdx.x == 0) {
    dpart[blk] = redD[0] + redD[1] + redD[2] + redD[3];
    cpart[blk] = redC[0] + redC[1] + redC[2] + redC[3];
  }
}

// ---- main: barrier-free LDS-free MFMA Gram; one batch per block (GB=1).
// Fragment loads hit the LOCAL XCD L2 (prep placement matched). Software
// prefetch distance 1. Per-(block,wave) partial output, no atomics.
template <int MODE>
__global__ __launch_bounds__(256, 2) void main_kernel(
    const float* __restrict__ dvec, const unsigned short* __restrict__ dbf2,
    const float* __restrict__ sq, const float* __restrict__ S,
    const float* __restrict__ W, float* __restrict__ npart) {
  const int tid = threadIdx.x;
  const int lane = tid & 63;
  const int wid = tid >> 6;
  const int wr = wid >> 1;
  const int wc = wid & 1;

  // XCD-chunked bijective swizzle (2304 = 8 * 288): XCD k gets bids
  // [288k, 288k+288) -> b in [8k, 8k+8) (t-fast) = the batches its L2 holds.
  const int orig = (int)blockIdx.x;
  const int bid = (orig & 7) * (NT * NB / 8) + (orig >> 3);
  const int t = bid % NT;
  const int b = bid / NT;
  int u = t, ti = 0;
  while (u >= 8 - ti) { u -= 8 - ti; ++ti; }
  const int tj = ti + u;
  const int brow = ti * 128;
  const int bcol = tj * 128;

  const int rtA0 = ti * 8 + wr * 4;   // A row-tiles (16 rows each)
  const int rtB0 = tj * 8 + wc * 4;   // B row-tiles (Gram columns)

  f32x4 acc[4][4];
  #pragma unroll
  for (int m = 0; m < 4; ++m)
    #pragma unroll
    for (int n = 0; n < 4; ++n) acc[m][n] = f32x4{0.f, 0.f, 0.f, 0.f};

  if (MODE == 0) {
    const unsigned short* pa =
        dbf2 + (((size_t)b * 8) * 64 + rtA0) * 512 + (size_t)lane * 8;
    const unsigned short* pb =
        dbf2 + (((size_t)b * 8) * 64 + rtB0) * 512 + (size_t)lane * 8;
    bf16x8 af[4], bf[4], nf[4];
    #pragma unroll
    for (int m = 0; m < 4; ++m)
      af[m] = *reinterpret_cast<const bf16x8*>(pa + m * 512);
    #pragma unroll
    for (int n = 0; n < 4; ++n)
      bf[n] = *reinterpret_cast<const bf16x8*>(pb + n * 512);
    #pragma unroll
    for (int kg = 0; kg < 8; ++kg) {
      if (kg < 7) {
        #pragma unroll
        for (int m = 0; m < 4; ++m)
          nf[m] = *reinterpret_cast<const bf16x8*>(pa + 32768 + m * 512);
      }
      #pragma unroll
      for (int n = 0; n < 4; ++n) {
        #pragma unroll
        for (int m = 0; m < 4; ++m)
          acc[m][n] = __builtin_amdgcn_mfma_f32_16x16x32_bf16(af[m], bf[n], acc[m][n], 0, 0, 0);
        if (kg < 7)
          bf[n] = *reinterpret_cast<const bf16x8*>(pb + 32768 + n * 512);  // bf[n] dead
      }
      if (kg < 7) {
        #pragma unroll
        for (int m = 0; m < 4; ++m) af[m] = nf[m];
        pa += 32768; pb += 32768;
      }
    }
  } else {
    const float* pbase = dvec + (size_t)b * NS * DD + (lane >> 4) * 8;
    #pragma unroll
    for (int kg = 0; kg < 8; ++kg) {
      bf16x8 af[4], bf[4];
      #pragma unroll
      for (int m = 0; m < 4; ++m) {
        const float* p = pbase + (size_t)((rtA0 + m) * 16 + (lane & 15)) * DD + kg * 32;
        float4 v0 = reinterpret_cast<const float4*>(p)[0];
        float4 v1 = reinterpret_cast<const float4*>(p)[1];
        af[m][0] = (short)f2bf(v0.x); af[m][1] = (short)f2bf(v0.y);
        af[m][2] = (short)f2bf(v0.z); af[m][3] = (short)f2bf(v0.w);
        af[m][4] = (short)f2bf(v1.x); af[m][5] = (short)f2bf(v1.y);
        af[m][6] = (short)f2bf(v1.z); af[m][7] = (short)f2bf(v1.w);
      }
      #pragma unroll
      for (int n = 0; n < 4; ++n) {
        const float* p = pbase + (size_t)((rtB0 + n) * 16 + (lane & 15)) * DD + kg * 32;
        float4 v0 = reinterpret_cast<const float4*>(p)[0];
        float4 v1 = reinterpret_cast<const float4*>(p)[1];
        bf[n][0] = (short)f2bf(v0.x); bf[n][1] = (short)f2bf(v0.y);
        bf[n][2] = (short)f2bf(v0.z); bf[n][3] = (short)f2bf(v0.w);
        bf[n][4] = (short)f2bf(v1.x); bf[n][5] = (short)f2bf(v1.y);
        bf[n][6] = (short)f2bf(v1.z); bf[n][7] = (short)f2bf(v1.w);
      }
      #pragma unroll
      for (int m = 0; m < 4; ++m)
        #pragma unroll
        for (int n = 0; n < 4; ++n)
          acc[m][n] = __builtin_amdgcn_mfma_f32_16x16x32_bf16(af[m], bf[n], acc[m][n], 0, 0, 0);
    }
  }

  // ---- epilogue, two-pass: branch-free d2 min scan; rare kd path under one
  // ballot. exp(-dist) is sub-f32-eps vs S once d2 > THR -> bit-identical. ----
  const float* sqb = sq + (size_t)b * NS;
  const int hi = lane >> 4, lo = lane & 15;
  float sqc[4];
  #pragma unroll
  for (int n = 0; n < 4; ++n) sqc[n] = sqb[bcol + wc * 64 + n * 16 + lo];
  float dmin = 1e30f;
  #pragma unroll
  for (int m = 0; m < 4; ++m) {
    #pragma unroll
    for (int j = 0; j < 4; ++j) {
      const int r = brow + wr * 64 + m * 16 + hi * 4 + j;
      const float sqr = sqb[r];
      #pragma unroll
      for (int n = 0; n < 4; ++n) {
        const int c = bcol + wc * 64 + n * 16 + lo;
        const float d2 = fmaxf(sqr + sqc[n] - 2.0f * acc[m][n][j], 0.0f);
        dmin = fminf(dmin, (r < c) ? d2 : 1e30f);
      }
    }
  }
  float wsum = 0.f;
  if (__any(dmin < THR)) {
    // pair (r,c), r<c: kd^2*(W[r][c]+W[c][r]) - 2*kd*(W[r][c]S[r][c]+W[c][r]S[c][r])
    float lsum = 0.f;
    #pragma unroll
    for (int m = 0; m < 4; ++m) {
      #pragma unroll
      for (int j = 0; j < 4; ++j) {
        const int r = brow + wr * 64 + m * 16 + hi * 4 + j;
        const float sqr = sqb[r];
        #pragma unroll
        for (int n = 0; n < 4; ++n) {
          const int c = bcol + wc * 64 + n * 16 + lo;
          const float d2 = fmaxf(sqr + sqc[n] - 2.0f * acc[m][n][j], 0.0f);
          if ((r < c) && (d2 < THR)) {
            const float kd = __expf(-sqrtf(d2));
            const float wrc = W[(size_t)r * NS + c];
            const float wcr = W[(size_t)c * NS + r];
            const float src_ = S[(size_t)r * NS + c];
            const float scr = S[(size_t)c * NS + r];
            lsum = fmaf(kd, kd * (wrc + wcr) - 2.0f * fmaf(wrc, src_, wcr * scr), lsum);
          }
        }
      }
    }
    #pragma unroll
    for (int off = 32; off > 0; off >>= 1) lsum += __shfl_xor(lsum, off, 64);
    wsum = lsum;
  }
  // unconditional per-(block,wave) partial (poison-safe, no atomics)
  if (lane == 0) npart[(size_t)bid * 4 + wid] = wsum;
}

// ---- final: npart[b*144 .. +144) per batch; out = sum_b 2*sqrt(C+n_b)/sqrt(D) ----
__global__ void final_kernel(const float* __restrict__ npart,
                             const float* __restrict__ dpart,
                             const float* __restrict__ cpart,
                             float* __restrict__ out) {
  const int lane = threadIdx.x;
  float dsum = 0.f, csum = 0.f;
  #pragma unroll
  for (int j = 0; j < 8; ++j) {
    dsum += dpart[lane + 64 * j];
    csum += cpart[lane + 64 * j];
  }
  #pragma unroll
  for (int off = 32; off > 0; off >>= 1) {
    dsum += __shfl_xor(dsum, off, 64);
    csum += __shfl_xor(csum, off, 64);
  }
  // lane b: reduce its batch's 36 tiles x 4 waves = 144 contiguous floats
  float nb = 0.f;
  const f32x4* np = reinterpret_cast<const f32x4*>(npart + (size_t)lane * 144);
  #pragma unroll
  for (int j = 0; j < 36; ++j) {
    f32x4 v = np[j];
    nb += v[0] + v[1] + v[2] + v[3];
  }
  float v = 2.0f * sqrtf(csum + nb);
  #pragma unroll
  for (int off = 32; off > 0; off >>= 1) v += __shfl_xor(v, off, 64);
  if (lane == 0) out[0] = v / sqrtf(dsum);
}

extern "C" void kernel_launch(void* const* d_in, const int* in_sizes, int n_in,
                              void* d_out, int out_size, void* d_ws, size_t ws_size,
                              hipStream_t stream) {
  const float* dvec = (const float*)d_in[0];
  const float* S = (const float*)d_in[1];
  const float* W = (const float*)d_in[2];
  float* out = (float*)d_out;

  const size_t bf_bytes = (size_t)NB * NS * DD * sizeof(unsigned short);  // 32 MiB
  const size_t sq_bytes = (size_t)NB * NS * sizeof(float);                // 256 KiB
  const size_t small_bytes = sq_bytes + (9216 + 512 + 512) * sizeof(float);
  const bool full = ws_size >= bf_bytes + small_bytes;

  unsigned short* dbf2;
  float* sqp;
  if (full) {
    dbf2 = (unsigned short*)d_ws;
    sqp = (float*)((char*)d_ws + bf_bytes);
  } else {
    dbf2 = nullptr;
    sqp = (float*)d_ws;
  }
  float* npart = sqp + (size_t)NB * NS;    // 9216 floats (2304 blocks x 4 waves)
  float* dpart = npart + 9216;             // 512
  float* cpart = dpart + 512;              // 512

  prep_kernel<<<4096 + 512, 256, 0, stream>>>(dvec, dbf2, sqp, S, W, dpart, cpart,
                                              full ? 1 : 0);
  if (full)
    main_kernel<0><<<NT * NB, 256, 0, stream>>>(dvec, dbf2, sqp, S, W, npart);
  else
    main_kernel<1><<<NT * NB, 256, 0, stream>>>(dvec, dbf2, sqp, S, W, npart);
  final_kernel<<<1, 64, 0, stream>>>(npart, dpart, cpart, out);
}

// Round 9
// 48.081 us; speedup vs baseline: 2.6220x; 1.1010x over previous
//
#include <hip/hip_runtime.h>
#include <hip/hip_bf16.h>

#define NB 64
#define NS 1024
#define DD 256
#define NT 36          // upper-triangular 8x8 tile count
#define THR 120.0f     // dist^2 below which exp(-dist) can matter

typedef __attribute__((ext_vector_type(4))) float f32x4;
typedef __attribute__((ext_vector_type(8))) short bf16x8;
typedef __attribute__((ext_vector_type(8))) unsigned short u16x8;
typedef __attribute__((ext_vector_type(4))) unsigned short u16x4;

__device__ __forceinline__ unsigned short f2bf(float x) {
  union { float f; unsigned int u; } c; c.f = x;
  unsigned int r = c.u + 0x7fffu + ((c.u >> 16) & 1u);
  return (unsigned short)(r >> 16);
}

// dbf2 layout (kg-major fragment blocks): block(b, kg, rt) = (b*8 + kg)*64 + rt,
// 512 bf16 each. Slot s (0..63) holds 8 bf16: row = rt*16 + (s&15),
// k = kg*32 + (s>>4)*8 + 0..7.  A wave's MFMA fragment load is ONE coalesced
// 1KB global_load_dwordx4; prep's fragment STORE is likewise one coalesced
// 1KB store per kg (lane l -> slot l), via an LDS transpose.

// ---- prep: blocks [0,1024): one 16-row tile per wave. Phase A: 16 coalesced
//      1KB row loads, per-row sq shuffle-reduce, bf16 cvt, XOR-swizzled LDS
//      write (conflict-free). Phase B: swizzled ds_read_b128 -> 8 coalesced
//      1KB fragment stores. Wave-private LDS region -> no barriers.
//      XCD-matched: XCD k (= px&7) writes batches [8k,8k+8) = main's readers.
//      blocks [1024,1536): denom2/C partials over W/S (no atomics). ----
__global__ __launch_bounds__(256) void prep_kernel(const float* __restrict__ din,
                                                   unsigned short* __restrict__ dbf2,
                                                   float* __restrict__ sq,
                                                   const float* __restrict__ S,
                                                   const float* __restrict__ W,
                                                   float* __restrict__ dpart,
                                                   float* __restrict__ cpart,
                                                   int write_bf) {
  const int px = (int)blockIdx.x;
  const int wid = (int)threadIdx.x >> 6;
  const int l = (int)threadIdx.x & 63;
  if (px < 1024) {
    __shared__ unsigned short lds[4][16][256];   // 4 waves x 8KB, wave-private
    unsigned short (*T)[256] = lds[wid];
    const int tb = (px & 7) * 128 + (px >> 3);
    const int task = tb * 4 + wid;               // b*64 + rt
    const int b = task >> 6, rt = task & 63;
    const float4* src =
        reinterpret_cast<const float4*>(din + ((size_t)b * NS + rt * 16) * DD) + l;
    #pragma unroll
    for (int r16 = 0; r16 < 16; ++r16) {
      float4 v = src[r16 * 64];                  // row stride 256 f = 64 float4
      float s = v.x * v.x + v.y * v.y + v.z * v.z + v.w * v.w;
      #pragma unroll
      for (int off = 32; off > 0; off >>= 1) s += __shfl_xor(s, off, 64);
      if (l == 0) sq[(size_t)b * NS + rt * 16 + r16] = s;
      if (write_bf) {
        // lane l holds data 8B-chunk d=l of this row; store at LDS 16B-chunk
        // (l>>1)^(r16&7), half l&1  (bank-conflict-free: full 512B row/wave)
        u16x4 o;
        o[0] = f2bf(v.x); o[1] = f2bf(v.y); o[2] = f2bf(v.z); o[3] = f2bf(v.w);
        const int cp = (l >> 1) ^ (r16 & 7);
        *reinterpret_cast<u16x4*>(&T[r16][cp * 8 + (l & 1) * 4]) = o;
      }
    }
    if (write_bf) {
      // fragment slot l of kg block = row (l&15), data 16B-chunk kg*4+(l>>4),
      // stored at LDS chunk ^(row&7) = ^(l&7). Then 1KB coalesced global store.
      unsigned short* dst = dbf2 + (((size_t)b * 8) * 64 + rt) * 512 + (size_t)l * 8;
      #pragma unroll
      for (int kg = 0; kg < 8; ++kg) {
        const int cc = (kg * 4 + (l >> 4)) ^ (l & 7);
        u16x8 frag = *reinterpret_cast<const u16x8*>(&T[l & 15][cc * 8]);
        *reinterpret_cast<u16x8*>(dst + (size_t)kg * 64 * 512) = frag;
      }
    }
    return;
  }
  // denomC partials: blk in [0,512), 256 thr x 2 float4 each
  const int blk = px - 1024;
  const int base = blk * 256 + (int)threadIdx.x;
  float dsum = 0.f, csum = 0.f;
  #pragma unroll
  for (int rpt = 0; rpt < 2; ++rpt) {
    const int idx = base + rpt * 131072;
    float4 w = reinterpret_cast<const float4*>(W)[idx];
    float4 s4 = reinterpret_cast<const float4*>(S)[idx];
    const int e0 = idx << 2;
    const int r = e0 >> 10, c0 = e0 & 1023;
    float wv[4] = {w.x, w.y, w.z, w.w};
    float sv[4] = {s4.x, s4.y, s4.z, s4.w};
    #pragma unroll
    for (int i = 0; i < 4; ++i) {
      const bool dg = (c0 + i) == r;
      const float a = wv[i] - (dg ? 1.0f : 0.0f);
      dsum = fmaf(a, a, dsum);
      const float bq = dg ? (1.0f - sv[i]) : sv[i];
      csum = fmaf(wv[i] * bq, bq, csum);   // W binary: W^2 == W
    }
  }
  #pragma unroll
  for (int off = 32; off > 0; off >>= 1) {
    dsum += __shfl_xor(dsum, off, 64);
    csum += __shfl_xor(csum, off, 64);
  }
  __shared__ float redD[4], redC[4];
  if (l == 0) { redD[wid] = dsum; redC[wid] = csum; }
  __syncthreads();
  if (threadIdx.x == 0) {
    dpart[blk] = redD[0] + redD[1] + redD[2] + redD[3];
    cpart[blk] = redC[0] + redC[1] + redC[2] + redC[3];
  }
}

// ---- main: barrier-free LDS-free MFMA Gram; one batch per block (GB=1).
// Fragment loads hit the LOCAL XCD L2 (prep placement matched). Software
// prefetch distance 1. Per-(block,wave) partial output, no atomics.
template <int MODE>
__global__ __launch_bounds__(256, 2) void main_kernel(
    const float* __restrict__ dvec, const unsigned short* __restrict__ dbf2,
    const float* __restrict__ sq, const float* __restrict__ S,
    const float* __restrict__ W, float* __restrict__ npart) {
  const int tid = threadIdx.x;
  const int lane = tid & 63;
  const int wid = tid >> 6;
  const int wr = wid >> 1;
  const int wc = wid & 1;

  // XCD-chunked bijective swizzle (2304 = 8 * 288): XCD k gets bids
  // [288k, 288k+288) -> b in [8k, 8k+8) (t-fast) = the batches its L2 holds.
  const int orig = (int)blockIdx.x;
  const int bid = (orig & 7) * (NT * NB / 8) + (orig >> 3);
  const int t = bid % NT;
  const int b = bid / NT;
  int u = t, ti = 0;
  while (u >= 8 - ti) { u -= 8 - ti; ++ti; }
  const int tj = ti + u;
  const int brow = ti * 128;
  const int bcol = tj * 128;

  const int rtA0 = ti * 8 + wr * 4;   // A row-tiles (16 rows each)
  const int rtB0 = tj * 8 + wc * 4;   // B row-tiles (Gram columns)

  f32x4 acc[4][4];
  #pragma unroll
  for (int m = 0; m < 4; ++m)
    #pragma unroll
    for (int n = 0; n < 4; ++n) acc[m][n] = f32x4{0.f, 0.f, 0.f, 0.f};

  if (MODE == 0) {
    const unsigned short* pa =
        dbf2 + (((size_t)b * 8) * 64 + rtA0) * 512 + (size_t)lane * 8;
    const unsigned short* pb =
        dbf2 + (((size_t)b * 8) * 64 + rtB0) * 512 + (size_t)lane * 8;
    bf16x8 af[4], bf[4], nf[4];
    #pragma unroll
    for (int m = 0; m < 4; ++m)
      af[m] = *reinterpret_cast<const bf16x8*>(pa + m * 512);
    #pragma unroll
    for (int n = 0; n < 4; ++n)
      bf[n] = *reinterpret_cast<const bf16x8*>(pb + n * 512);
    #pragma unroll
    for (int kg = 0; kg < 8; ++kg) {
      if (kg < 7) {
        #pragma unroll
        for (int m = 0; m < 4; ++m)
          nf[m] = *reinterpret_cast<const bf16x8*>(pa + 32768 + m * 512);
      }
      #pragma unroll
      for (int n = 0; n < 4; ++n) {
        #pragma unroll
        for (int m = 0; m < 4; ++m)
          acc[m][n] = __builtin_amdgcn_mfma_f32_16x16x32_bf16(af[m], bf[n], acc[m][n], 0, 0, 0);
        if (kg < 7)
          bf[n] = *reinterpret_cast<const bf16x8*>(pb + 32768 + n * 512);  // bf[n] dead
      }
      if (kg < 7) {
        #pragma unroll
        for (int m = 0; m < 4; ++m) af[m] = nf[m];
        pa += 32768; pb += 32768;
      }
    }
  } else {
    const float* pbase = dvec + (size_t)b * NS * DD + (lane >> 4) * 8;
    #pragma unroll
    for (int kg = 0; kg < 8; ++kg) {
      bf16x8 af[4], bf[4];
      #pragma unroll
      for (int m = 0; m < 4; ++m) {
        const float* p = pbase + (size_t)((rtA0 + m) * 16 + (lane & 15)) * DD + kg * 32;
        float4 v0 = reinterpret_cast<const float4*>(p)[0];
        float4 v1 = reinterpret_cast<const float4*>(p)[1];
        af[m][0] = (short)f2bf(v0.x); af[m][1] = (short)f2bf(v0.y);
        af[m][2] = (short)f2bf(v0.z); af[m][3] = (short)f2bf(v0.w);
        af[m][4] = (short)f2bf(v1.x); af[m][5] = (short)f2bf(v1.y);
        af[m][6] = (short)f2bf(v1.z); af[m][7] = (short)f2bf(v1.w);
      }
      #pragma unroll
      for (int n = 0; n < 4; ++n) {
        const float* p = pbase + (size_t)((rtB0 + n) * 16 + (lane & 15)) * DD + kg * 32;
        float4 v0 = reinterpret_cast<const float4*>(p)[0];
        float4 v1 = reinterpret_cast<const float4*>(p)[1];
        bf[n][0] = (short)f2bf(v0.x); bf[n][1] = (short)f2bf(v0.y);
        bf[n][2] = (short)f2bf(v0.z); bf[n][3] = (short)f2bf(v0.w);
        bf[n][4] = (short)f2bf(v1.x); bf[n][5] = (short)f2bf(v1.y);
        bf[n][6] = (short)f2bf(v1.z); bf[n][7] = (short)f2bf(v1.w);
      }
      #pragma unroll
      for (int m = 0; m < 4; ++m)
        #pragma unroll
        for (int n = 0; n < 4; ++n)
          acc[m][n] = __builtin_amdgcn_mfma_f32_16x16x32_bf16(af[m], bf[n], acc[m][n], 0, 0, 0);
    }
  }

  // ---- epilogue, two-pass: branch-free d2 min scan; rare kd path under one
  // ballot. exp(-dist) is sub-f32-eps vs S once d2 > THR -> bit-identical. ----
  const float* sqb = sq + (size_t)b * NS;
  const int hi = lane >> 4, lo = lane & 15;
  float sqc[4];
  #pragma unroll
  for (int n = 0; n < 4; ++n) sqc[n] = sqb[bcol + wc * 64 + n * 16 + lo];
  float dmin = 1e30f;
  #pragma unroll
  for (int m = 0; m < 4; ++m) {
    #pragma unroll
    for (int j = 0; j < 4; ++j) {
      const int r = brow + wr * 64 + m * 16 + hi * 4 + j;
      const float sqr = sqb[r];
      #pragma unroll
      for (int n = 0; n < 4; ++n) {
        const int c = bcol + wc * 64 + n * 16 + lo;
        const float d2 = fmaxf(sqr + sqc[n] - 2.0f * acc[m][n][j], 0.0f);
        dmin = fminf(dmin, (r < c) ? d2 : 1e30f);
      }
    }
  }
  float wsum = 0.f;
  if (__any(dmin < THR)) {
    // pair (r,c), r<c: kd^2*(W[r][c]+W[c][r]) - 2*kd*(W[r][c]S[r][c]+W[c][r]S[c][r])
    float lsum = 0.f;
    #pragma unroll
    for (int m = 0; m < 4; ++m) {
      #pragma unroll
      for (int j = 0; j < 4; ++j) {
        const int r = brow + wr * 64 + m * 16 + hi * 4 + j;
        const float sqr = sqb[r];
        #pragma unroll
        for (int n = 0; n < 4; ++n) {
          const int c = bcol + wc * 64 + n * 16 + lo;
          const float d2 = fmaxf(sqr + sqc[n] - 2.0f * acc[m][n][j], 0.0f);
          if ((r < c) && (d2 < THR)) {
            const float kd = __expf(-sqrtf(d2));
            const float wrc = W[(size_t)r * NS + c];
            const float wcr = W[(size_t)c * NS + r];
            const float src_ = S[(size_t)r * NS + c];
            const float scr = S[(size_t)c * NS + r];
            lsum = fmaf(kd, kd * (wrc + wcr) - 2.0f * fmaf(wrc, src_, wcr * scr), lsum);
          }
        }
      }
    }
    #pragma unroll
    for (int off = 32; off > 0; off >>= 1) lsum += __shfl_xor(lsum, off, 64);
    wsum = lsum;
  }
  // unconditional per-(block,wave) partial (poison-safe, no atomics)
  if (lane == 0) npart[(size_t)bid * 4 + wid] = wsum;
}

// ---- final: npart[b*144 .. +144) per batch; out = sum_b 2*sqrt(C+n_b)/sqrt(D) ----
__global__ void final_kernel(const float* __restrict__ npart,
                             const float* __restrict__ dpart,
                             const float* __restrict__ cpart,
                             float* __restrict__ out) {
  const int lane = threadIdx.x;
  float dsum = 0.f, csum = 0.f;
  #pragma unroll
  for (int j = 0; j < 8; ++j) {
    dsum += dpart[lane + 64 * j];
    csum += cpart[lane + 64 * j];
  }
  #pragma unroll
  for (int off = 32; off > 0; off >>= 1) {
    dsum += __shfl_xor(dsum, off, 64);
    csum += __shfl_xor(csum, off, 64);
  }
  // lane b: reduce its batch's 36 tiles x 4 waves = 144 contiguous floats
  float nb = 0.f;
  const f32x4* np = reinterpret_cast<const f32x4*>(npart + (size_t)lane * 144);
  #pragma unroll
  for (int j = 0; j < 36; ++j) {
    f32x4 v = np[j];
    nb += v[0] + v[1] + v[2] + v[3];
  }
  float v = 2.0f * sqrtf(csum + nb);
  #pragma unroll
  for (int off = 32; off > 0; off >>= 1) v += __shfl_xor(v, off, 64);
  if (lane == 0) out[0] = v / sqrtf(dsum);
}

extern "C" void kernel_launch(void* const* d_in, const int* in_sizes, int n_in,
                              void* d_out, int out_size, void* d_ws, size_t ws_size,
                              hipStream_t stream) {
  const float* dvec = (const float*)d_in[0];
  const float* S = (const float*)d_in[1];
  const float* W = (const float*)d_in[2];
  float* out = (float*)d_out;

  const size_t bf_bytes = (size_t)NB * NS * DD * sizeof(unsigned short);  // 32 MiB
  const size_t sq_bytes = (size_t)NB * NS * sizeof(float);                // 256 KiB
  const size_t small_bytes = sq_bytes + (9216 + 512 + 512) * sizeof(float);
  const bool full = ws_size >= bf_bytes + small_bytes;

  unsigned short* dbf2;
  float* sqp;
  if (full) {
    dbf2 = (unsigned short*)d_ws;
    sqp = (float*)((char*)d_ws + bf_bytes);
  } else {
    dbf2 = nullptr;
    sqp = (float*)d_ws;
  }
  float* npart = sqp + (size_t)NB * NS;    // 9216 floats (2304 blocks x 4 waves)
  float* dpart = npart + 9216;             // 512
  float* cpart = dpart + 512;              // 512

  prep_kernel<<<1024 + 512, 256, 0, stream>>>(dvec, dbf2, sqp, S, W, dpart, cpart,
                                              full ? 1 : 0);
  if (full)
    main_kernel<0><<<NT * NB, 256, 0, stream>>>(dvec, dbf2, sqp, S, W, npart);
  else
    main_kernel<1><<<NT * NB, 256, 0, stream>>>(dvec, dbf2, sqp, S, W, npart);
  final_kernel<<<1, 64, 0, stream>>>(npart, dpart, cpart, out);
}